// Round 13
// baseline (324.573 us; speedup 1.0000x reference)
//
#include <hip/hip_runtime.h>

// Decoder: frames[m,c,k,l] = sum_n (mix[m,n,k]*mask[m,c,n,k]) * W[l,n]
// then overlap-add (hop=8) into out[m,c,t], T = (K-1)*8+16 = 128008.
// M=4 C=2 N=512 K=16000 L=16.
//
// LDS-SHARED-MIX, COARSE-STEP (r12 with 7 barriers instead of 32):
//  - block = 512 threads = 8 waves = (g in 0..3 n-segments) x (c in 0..1);
//    each wave accumulates acc[16] for ONE c over its 128 n's.
//  - k-loop = 4 steps of 32 n-rows. Stage buffer = 32 KB (4 g x 32 rows x
//    64 lanes). Per step: issue the NEXT step's 16 mix stage-loads at the
//    top of compute (latency hides under ~17K cycles of FMA+DS work),
//    compute 4 groups of 8 n (mask streamed from global inside the phase,
//    no barrier interaction), then barrier -> ds_write stage -> barrier.
//    7 barriers total per block vs r12's 32 -> the drain lockstep that ate
//    r12's traffic win (393 vs 524 MB both timed 81 us) mostly vanishes.
//  - vector-path bytes = 393 MB mandatory minimum (mix once via LDS share,
//    mask once); fabric model: ~6.45 TB/s streaming service -> ~61 us floor.
//  - 1 k per lane (BK=64), grid 1000, launch_bounds(512,8): acc16+stage16+
//    mask8+addr ~58 VGPR < 64 -> 4 blocks/CU x 8 waves = 32 waves/CU;
//    LDS 32 KB x 4 = 128 KB < 160.
// W via scalar path (uniform address -> s_load float4, constant cache).
// Reduction: per c, waves g=1..3 dump to LDS (stage memory reused), wave
// g=0 of each c combines + overlap-adds in-register via shfl_up. Block
// boundary head/tail partials -> d_ws; boundary_kernel combines them:
// every out element written exactly once with '=' (no memset, no atomics).

#define M_   4
#define C_   2
#define N_   512
#define K_   16000
#define L_   16
#define HOP  8
#define T_   ((K_ - 1) * HOP + L_)   // 128008
#define BK   64                      // frames per block (1 per lane)
#define NB   (K_ / BK)               // 250 k-blocks per m
#define GRID (M_ * NB)               // 1000
#define NPW  128                     // n's per g-segment
#define RPS  32                      // n-rows staged per step
#define NSTEP (NPW / RPS)            // 4
#define RSTRIDE 20                   // reduce-buffer lane stride (floats)
#define WS_TAIL_OFF (M_ * C_ * NB * 8)

__global__ __launch_bounds__(512, 8)
void decoder_kernel(const float* __restrict__ mix,   // [M][N][K]
                    const float* __restrict__ mask,  // [M][C][N][K]
                    const float* __restrict__ Wg,    // [L][N]
                    float* __restrict__ out,         // [M][C][T]
                    float* __restrict__ ws) {
    __shared__ float lds[8192];      // stage 4g x 32rows x 64 = 32 KB; reduce reuses

    const int tid  = threadIdx.x;
    const int lane = tid & 63;
    const int w    = tid >> 6;       // 0..7
    const int c    = w >> 2;         // 0..1
    const int g    = w & 3;          // 0..3 (n-segment)
    const int m    = blockIdx.x / NB;
    const int bb   = blockIdx.x % NB;
    const int k0   = bb * BK;
    const int kk   = k0 + lane;

    float acc[16];
    #pragma unroll
    for (int i = 0; i < 16; ++i) acc[i] = 0.f;

    const int n0w  = g * NPW;
    const int n0wU = __builtin_amdgcn_readfirstlane(n0w);  // uniform -> s_load

    const float* pmix = mix  + (size_t)m * N_ * K_ + (size_t)n0w * K_ + kk;
    const float* pmsk = mask + ((size_t)(m * C_ + c) * N_ + n0w) * K_ + kk;

    float* stg = &lds[g * (RPS * 64)];   // row r (0..31) at stg[r*64+lane]

    // ---- prologue: stage step 0 (c=0 wave: rows 0..15, c=1: rows 16..31)
    float sr[16];
    #pragma unroll
    for (int i = 0; i < 16; ++i)
        sr[i] = pmix[(size_t)(c * 16 + i) * K_];
    #pragma unroll
    for (int i = 0; i < 16; ++i)
        stg[(c * 16 + i) * 64 + lane] = sr[i];
    __syncthreads();

    #pragma unroll 1
    for (int st = 0; st < NSTEP; ++st) {
        // issue NEXT step's stage loads early -> latency hides under compute
        if (st + 1 < NSTEP) {
            #pragma unroll
            for (int i = 0; i < 16; ++i)
                sr[i] = pmix[(size_t)((st + 1) * RPS + c * 16 + i) * K_];
        }

        // ---- compute this step: 4 groups of 8 n ----
        #pragma unroll
        for (int grp = 0; grp < 4; ++grp) {
            float a[8];
            #pragma unroll
            for (int j = 0; j < 8; ++j)
                a[j] = pmsk[(size_t)(st * RPS + grp * 8 + j) * K_];
            #pragma unroll
            for (int chh = 0; chh < 2; ++chh) {
                float s[4];
                #pragma unroll
                for (int j = 0; j < 4; ++j)
                    s[j] = stg[(grp * 8 + chh * 4 + j) * 64 + lane] * a[chh * 4 + j];
                const int nbase = n0wU + st * RPS + grp * 8 + chh * 4;  // scalar
                #pragma unroll
                for (int l = 0; l < L_; ++l) {
                    const float4 w4 = *(const float4*)&Wg[l * N_ + nbase]; // s_load
                    acc[l] = fmaf(s[0], w4.x, acc[l]);
                    acc[l] = fmaf(s[1], w4.y, acc[l]);
                    acc[l] = fmaf(s[2], w4.z, acc[l]);
                    acc[l] = fmaf(s[3], w4.w, acc[l]);
                }
            }
        }

        // ---- publish next step's stage ----
        if (st + 1 < NSTEP) {
            __syncthreads();         // all waves done reading current stage
            #pragma unroll
            for (int i = 0; i < 16; ++i)
                stg[(c * 16 + i) * 64 + lane] = sr[i];
            __syncthreads();         // stage visible to both c-waves
        }
    }

    // ---- reduction across g within each c (stage memory reused) ----
    __syncthreads();
    if (g > 0) {
        float* rb = &lds[((c * 3 + (g - 1)) * 64 + lane) * RSTRIDE];
        #pragma unroll
        for (int i = 0; i < 4; ++i)
            *(float4*)&rb[i * 4] = make_float4(acc[i*4], acc[i*4+1],
                                               acc[i*4+2], acc[i*4+3]);
    }
    __syncthreads();

    if (g == 0) {                    // one wave per c runs the epilogue
        #pragma unroll
        for (int r = 0; r < 3; ++r) {
            const float* rb = &lds[((c * 3 + r) * 64 + lane) * RSTRIDE];
            #pragma unroll
            for (int i = 0; i < 4; ++i) {
                const float4 v = *(const float4*)&rb[i * 4];
                acc[i*4]   += v.x;  acc[i*4+1] += v.y;
                acc[i*4+2] += v.z;  acc[i*4+3] += v.w;
            }
        }

        // ---- overlap-add: t = k*8+j = frames[k][j] + frames[k-1][8+j] ----
        float* ob = out + (size_t)(m * C_ + c) * T_ + (size_t)kk * HOP;
        float cmb[8];
        #pragma unroll
        for (int j = 0; j < 8; ++j) {
            const float pv = __shfl_up(acc[8 + j], 1);   // frames[kk-1][8+j]
            cmb[j] = acc[j] + pv;
        }
        if (lane == 0) {
            float* hb = ws + (size_t)((m * C_ + c) * NB + bb) * 8;
            *(float4*)&hb[0] = make_float4(acc[0], acc[1], acc[2], acc[3]);
            *(float4*)&hb[4] = make_float4(acc[4], acc[5], acc[6], acc[7]);
        } else {
            *(float4*)&ob[0] = make_float4(cmb[0], cmb[1], cmb[2], cmb[3]);
            *(float4*)&ob[4] = make_float4(cmb[4], cmb[5], cmb[6], cmb[7]);
        }
        if (lane == 63) {
            float* tb = ws + WS_TAIL_OFF + (size_t)((m * C_ + c) * NB + bb) * 8;
            *(float4*)&tb[0] = make_float4(acc[8],  acc[9],  acc[10], acc[11]);
            *(float4*)&tb[4] = make_float4(acc[12], acc[13], acc[14], acc[15]);
        }
    }
}

// out[bb*512 + j] = head[bb] + tail[bb-1]; global tail = tail[NB-1].
__global__ __launch_bounds__(256)
void boundary_kernel(const float* __restrict__ ws, float* __restrict__ out) {
    const int id = blockIdx.x * 256 + threadIdx.x;
    const int total = M_ * C_ * NB * 8;
    if (id >= total) return;
    const int j  = id & 7;
    const int bb = (id >> 3) % NB;
    const int mc = (id >> 3) / NB;
    float v = ws[(size_t)(mc * NB + bb) * 8 + j];
    if (bb > 0) v += ws[WS_TAIL_OFF + (size_t)(mc * NB + bb - 1) * 8 + j];
    out[(size_t)mc * T_ + (size_t)bb * (BK * HOP) + j] = v;
    if (bb == NB - 1) {
        out[(size_t)mc * T_ + (size_t)K_ * HOP + j] =
            ws[WS_TAIL_OFF + (size_t)(mc * NB + bb) * 8 + j];
    }
}

extern "C" void kernel_launch(void* const* d_in, const int* in_sizes, int n_in,
                              void* d_out, int out_size, void* d_ws, size_t ws_size,
                              hipStream_t stream) {
    const float* mix  = (const float*)d_in[0];
    const float* mask = (const float*)d_in[1];
    const float* Wg   = (const float*)d_in[2];
    float* out = (float*)d_out;
    float* ws  = (float*)d_ws;

    decoder_kernel<<<dim3(GRID), dim3(512), 0, stream>>>(mix, mask, Wg, out, ws);
    boundary_kernel<<<dim3((M_ * C_ * NB * 8 + 255) / 256), dim3(256), 0, stream>>>(ws, out);
}

// Round 14
// 141.865 us; speedup vs baseline: 2.2879x; 2.2879x over previous
//
#include <hip/hip_runtime.h>

// Decoder: frames[m,c,k,l] = sum_n (mix[m,n,k]*mask[m,c,n,k]) * W[l,n]
// then overlap-add (hop=8) into out[m,c,t], T = (K-1)*8+16 = 128008.
// M=4 C=2 N=512 K=16000 L=16.
//
// LDS-SHARED-MIX, 16-ROW STEPS (r13 rebudgeted: sr[16] blew the 64-VGPR
// cap of 8 waves/EU -> VGPR_Count=32 + 697 MB scratch writes; this keeps
// per-wave live state ~52 regs):
//  - block = 512 threads = 8 waves = (g in 0..3 n-segments) x (c in 0..1);
//    each wave accumulates acc[16] for ONE c over its 128 n's.
//  - k-loop = 8 steps of 16 n-rows. Stage buffer 16 KB (4g x 16rows x 64).
//    Per step: issue the NEXT step's 8 mix stage-loads (sr[8], c-split) at
//    the top of compute -> ~500 cy latency hides under ~8.5K cy of FMA+DS;
//    compute 2 groups of 8 n (mask a[8] streamed inside the phase); then
//    barrier -> ds_write -> barrier. 15 barriers vs r12's 32.
//  - vector-path bytes = 393 MB mandatory minimum (mix once, mask once);
//    fabric floor ~61 us at the measured ~6.45 TB/s streaming service.
//  - 1 k per lane (BK=64), grid 1000, launch_bounds(512,8):
//    acc16+sr8+a8+s4+addr ~52 VGPR < 64 -> 32 waves/CU; LDS 30.7 KB.
// W via scalar path (uniform address -> s_load float4, constant cache).
// Reduction: per c, waves g=1..3 dump to LDS (stage memory reused), wave
// g=0 of each c combines + overlap-adds in-register via shfl_up. Block
// boundary head/tail partials -> d_ws; boundary_kernel combines them:
// every out element written exactly once with '=' (no memset, no atomics).

#define M_   4
#define C_   2
#define N_   512
#define K_   16000
#define L_   16
#define HOP  8
#define T_   ((K_ - 1) * HOP + L_)   // 128008
#define BK   64                      // frames per block (1 per lane)
#define NB   (K_ / BK)               // 250 k-blocks per m
#define GRID (M_ * NB)               // 1000
#define NPW  128                     // n's per g-segment
#define RPS  16                      // n-rows staged per step
#define NSTEP (NPW / RPS)            // 8
#define RSTRIDE 20                   // reduce-buffer lane stride (floats)
#define WS_TAIL_OFF (M_ * C_ * NB * 8)

__global__ __launch_bounds__(512, 8)
void decoder_kernel(const float* __restrict__ mix,   // [M][N][K]
                    const float* __restrict__ mask,  // [M][C][N][K]
                    const float* __restrict__ Wg,    // [L][N]
                    float* __restrict__ out,         // [M][C][T]
                    float* __restrict__ ws) {
    __shared__ float lds[7680];      // stage 4g x 16rows x 64 = 16 KB; reduce reuses

    const int tid  = threadIdx.x;
    const int lane = tid & 63;
    const int w    = tid >> 6;       // 0..7
    const int c    = w >> 2;         // 0..1
    const int g    = w & 3;          // 0..3 (n-segment)
    const int m    = blockIdx.x / NB;
    const int bb   = blockIdx.x % NB;
    const int k0   = bb * BK;
    const int kk   = k0 + lane;

    float acc[16];
    #pragma unroll
    for (int i = 0; i < 16; ++i) acc[i] = 0.f;

    const int n0w  = g * NPW;
    const int n0wU = __builtin_amdgcn_readfirstlane(n0w);  // uniform -> s_load

    const float* pmix = mix  + (size_t)m * N_ * K_ + (size_t)n0w * K_ + kk;
    const float* pmsk = mask + ((size_t)(m * C_ + c) * N_ + n0w) * K_ + kk;

    float* stg = &lds[g * (RPS * 64)];   // row r (0..15) at stg[r*64+lane]

    // ---- prologue: stage step 0 (c=0 wave: rows 0..7, c=1: rows 8..15)
    float sr[8];
    #pragma unroll
    for (int i = 0; i < 8; ++i)
        sr[i] = pmix[(size_t)(c * 8 + i) * K_];
    #pragma unroll
    for (int i = 0; i < 8; ++i)
        stg[(c * 8 + i) * 64 + lane] = sr[i];
    __syncthreads();

    #pragma unroll 1
    for (int st = 0; st < NSTEP; ++st) {
        // issue NEXT step's stage loads early -> latency hides under compute
        if (st + 1 < NSTEP) {
            #pragma unroll
            for (int i = 0; i < 8; ++i)
                sr[i] = pmix[(size_t)((st + 1) * RPS + c * 8 + i) * K_];
        }

        // ---- compute this step: 2 groups of 8 n ----
        #pragma unroll
        for (int grp = 0; grp < 2; ++grp) {
            float a[8];
            #pragma unroll
            for (int j = 0; j < 8; ++j)
                a[j] = pmsk[(size_t)(st * RPS + grp * 8 + j) * K_];
            #pragma unroll
            for (int chh = 0; chh < 2; ++chh) {
                float s[4];
                #pragma unroll
                for (int j = 0; j < 4; ++j)
                    s[j] = stg[(grp * 8 + chh * 4 + j) * 64 + lane] * a[chh * 4 + j];
                const int nbase = n0wU + st * RPS + grp * 8 + chh * 4;  // scalar
                #pragma unroll
                for (int l = 0; l < L_; ++l) {
                    const float4 w4 = *(const float4*)&Wg[l * N_ + nbase]; // s_load
                    acc[l] = fmaf(s[0], w4.x, acc[l]);
                    acc[l] = fmaf(s[1], w4.y, acc[l]);
                    acc[l] = fmaf(s[2], w4.z, acc[l]);
                    acc[l] = fmaf(s[3], w4.w, acc[l]);
                }
            }
        }

        // ---- publish next step's stage ----
        if (st + 1 < NSTEP) {
            __syncthreads();         // all waves done reading current stage
            #pragma unroll
            for (int i = 0; i < 8; ++i)
                stg[(c * 8 + i) * 64 + lane] = sr[i];
            __syncthreads();         // stage visible to both c-waves
        }
    }

    // ---- reduction across g within each c (stage memory reused) ----
    __syncthreads();
    if (g > 0) {
        float* rb = &lds[((c * 3 + (g - 1)) * 64 + lane) * RSTRIDE];
        #pragma unroll
        for (int i = 0; i < 4; ++i)
            *(float4*)&rb[i * 4] = make_float4(acc[i*4], acc[i*4+1],
                                               acc[i*4+2], acc[i*4+3]);
    }
    __syncthreads();

    if (g == 0) {                    // one wave per c runs the epilogue
        #pragma unroll
        for (int r = 0; r < 3; ++r) {
            const float* rb = &lds[((c * 3 + r) * 64 + lane) * RSTRIDE];
            #pragma unroll
            for (int i = 0; i < 4; ++i) {
                const float4 v = *(const float4*)&rb[i * 4];
                acc[i*4]   += v.x;  acc[i*4+1] += v.y;
                acc[i*4+2] += v.z;  acc[i*4+3] += v.w;
            }
        }

        // ---- overlap-add: t = k*8+j = frames[k][j] + frames[k-1][8+j] ----
        float* ob = out + (size_t)(m * C_ + c) * T_ + (size_t)kk * HOP;
        float cmb[8];
        #pragma unroll
        for (int j = 0; j < 8; ++j) {
            const float pv = __shfl_up(acc[8 + j], 1);   // frames[kk-1][8+j]
            cmb[j] = acc[j] + pv;
        }
        if (lane == 0) {
            float* hb = ws + (size_t)((m * C_ + c) * NB + bb) * 8;
            *(float4*)&hb[0] = make_float4(acc[0], acc[1], acc[2], acc[3]);
            *(float4*)&hb[4] = make_float4(acc[4], acc[5], acc[6], acc[7]);
        } else {
            *(float4*)&ob[0] = make_float4(cmb[0], cmb[1], cmb[2], cmb[3]);
            *(float4*)&ob[4] = make_float4(cmb[4], cmb[5], cmb[6], cmb[7]);
        }
        if (lane == 63) {
            float* tb = ws + WS_TAIL_OFF + (size_t)((m * C_ + c) * NB + bb) * 8;
            *(float4*)&tb[0] = make_float4(acc[8],  acc[9],  acc[10], acc[11]);
            *(float4*)&tb[4] = make_float4(acc[12], acc[13], acc[14], acc[15]);
        }
    }
}

// out[bb*512 + j] = head[bb] + tail[bb-1]; global tail = tail[NB-1].
__global__ __launch_bounds__(256)
void boundary_kernel(const float* __restrict__ ws, float* __restrict__ out) {
    const int id = blockIdx.x * 256 + threadIdx.x;
    const int total = M_ * C_ * NB * 8;
    if (id >= total) return;
    const int j  = id & 7;
    const int bb = (id >> 3) % NB;
    const int mc = (id >> 3) / NB;
    float v = ws[(size_t)(mc * NB + bb) * 8 + j];
    if (bb > 0) v += ws[WS_TAIL_OFF + (size_t)(mc * NB + bb - 1) * 8 + j];
    out[(size_t)mc * T_ + (size_t)bb * (BK * HOP) + j] = v;
    if (bb == NB - 1) {
        out[(size_t)mc * T_ + (size_t)K_ * HOP + j] =
            ws[WS_TAIL_OFF + (size_t)(mc * NB + bb) * 8 + j];
    }
}

extern "C" void kernel_launch(void* const* d_in, const int* in_sizes, int n_in,
                              void* d_out, int out_size, void* d_ws, size_t ws_size,
                              hipStream_t stream) {
    const float* mix  = (const float*)d_in[0];
    const float* mask = (const float*)d_in[1];
    const float* Wg   = (const float*)d_in[2];
    float* out = (float*)d_out;
    float* ws  = (float*)d_ws;

    decoder_kernel<<<dim3(GRID), dim3(512), 0, stream>>>(mix, mask, Wg, out, ws);
    boundary_kernel<<<dim3((M_ * C_ * NB * 8 + 255) / 256), dim3(256), 0, stream>>>(ws, out);
}

// Round 15
// 80.989 us; speedup vs baseline: 4.0076x; 1.7517x over previous
//
#include <hip/hip_runtime.h>

// Decoder: frames[m,c,k,l] = sum_n (mix[m,n,k]*mask[m,c,n,k]) * W[l,n]
// then overlap-add (hop=8) into out[m,c,t], T = (K-1)*8+16 = 128008.
// M=4 C=2 N=512 K=16000 L=16.
//
// SESSION-BEST (r8, 80.6 us): occupancy-first streaming design.
// One k per lane, acc[16] scalar, dword streaming loads -> ~50-60 VGPR,
// __launch_bounds__(256,8) caps at 64 -> 8 waves/SIMD = 32 waves/CU.
// BK=64 frames/block, 4 waves each own 128 n's, grid = 2000 = 125*16:
// c in blockIdx BIT 3 (bijective since 1000 units % 8 == 0) so the two
// c-blocks of a unit are 8 apart -> same XCD -> mix re-read is an L2 hit.
// W read via scalar path (uniform address -> s_load through constant
// cache; FMA takes the SGPR operand directly) -- no LDS in the hot loop.
// LDS only for the 15.4 KB cross-wave reduce (stride 20 floats keeps
// float4 alignment; 8 blocks/CU -> 123 KB < 160). Wave 0 overlap-adds
// in-register via shfl_up; block-boundary head/tail partials -> d_ws;
// boundary_kernel combines them: every out element written exactly once
// with '=' (no memset, no atomics, graph-replay-safe).
//
// Plateau evidence (r2..r14): r8 (524 MB streamed, no hot-loop barriers)
// and r12 (393 MB via LDS-shared mix, 32 barriers) both land at ~81 us;
// all attempts to combine 393 MB with barrier-free streaming hit the
// 64-VGPR occupancy cliff (r9/r11/r13/r14 spill or rematerialize).
// ~80 us = ~6.5 TB/s effective vector-path service = the practical limit.

#define M_   4
#define C_   2
#define N_   512
#define K_   16000
#define L_   16
#define HOP  8
#define T_   ((K_ - 1) * HOP + L_)   // 128008
#define BK   64                      // frames per block (1 per lane)
#define NSEG 4                       // waves per block
#define NPW  (N_ / NSEG)             // 128
#define NCH  (NPW / 4)               // 32 chunks of 4 n's
#define NB   (K_ / BK)               // 250 k-blocks per m
#define NUNITS (M_ * NB)             // 1000 (divisible by 8 -> no pad)
#define GRID (NUNITS * C_)           // 2000 = 125 * 16
#define RSTRIDE 20                   // reduce-buffer lane stride (floats)
#define WS_TAIL_OFF (M_ * C_ * NB * 8)

__global__ __launch_bounds__(256, 8)
void decoder_kernel(const float* __restrict__ mix,   // [M][N][K]
                    const float* __restrict__ mask,  // [M][C][N][K]
                    const float* __restrict__ Wg,    // [L][N]
                    float* __restrict__ out,         // [M][C][T]
                    float* __restrict__ ws) {
    __shared__ float lds[3 * 64 * RSTRIDE];          // 3840 floats = 15.4 KB

    const int tid  = threadIdx.x;
    const int lane = tid & 63;
    const int w    = tid >> 6;
    const int bidx = blockIdx.x;
    // c-pair 8 apart (same XCD): unit = (bidx>>4)*8 + (bidx&7), c = bit3.
    const int c    = (bidx >> 3) & 1;
    const int unit = ((bidx >> 4) << 3) | (bidx & 7);   // 0..999, bijective
    const int m    = unit / NB;
    const int bb   = unit % NB;
    const int k0   = bb * BK;

    float acc[16];
    #pragma unroll
    for (int i = 0; i < 16; ++i) acc[i] = 0.f;

    const int n0w  = w * NPW;
    const int n0wU = __builtin_amdgcn_readfirstlane(n0w);  // uniform -> s_load
    const int kk   = k0 + lane;
    const float* pm = mix  + (size_t)m * N_ * K_ + (size_t)n0w * K_ + kk;
    const float* pk = mask + ((size_t)(m * C_ + c) * N_ + n0w) * K_ + kk;

    #pragma unroll 2
    for (int ch = 0; ch < NCH; ++ch) {
        float mv[4], av[4];
        #pragma unroll
        for (int j = 0; j < 4; ++j) {
            mv[j] = pm[(size_t)j * K_];
            av[j] = pk[(size_t)j * K_];
        }
        float s[4];
        #pragma unroll
        for (int j = 0; j < 4; ++j) s[j] = mv[j] * av[j];

        const int nbase = n0wU + ch * 4;                   // scalar
        #pragma unroll
        for (int l = 0; l < L_; ++l) {
            const float4 w4 = *(const float4*)&Wg[l * N_ + nbase];  // s_load
            acc[l] = fmaf(s[0], w4.x, acc[l]);
            acc[l] = fmaf(s[1], w4.y, acc[l]);
            acc[l] = fmaf(s[2], w4.z, acc[l]);
            acc[l] = fmaf(s[3], w4.w, acc[l]);
        }
        pm += (size_t)4 * K_;
        pk += (size_t)4 * K_;
    }

    // ---- cross-wave reduction through LDS ----
    __syncthreads();
    if (w > 0) {
        float* rb = &lds[(w - 1) * (64 * RSTRIDE) + lane * RSTRIDE];
        #pragma unroll
        for (int i = 0; i < 4; ++i)
            *(float4*)&rb[i * 4] = make_float4(acc[i*4], acc[i*4+1],
                                               acc[i*4+2], acc[i*4+3]);
    }
    __syncthreads();

    if (w == 0) {
        #pragma unroll
        for (int r = 0; r < 3; ++r) {
            const float* rb = &lds[r * (64 * RSTRIDE) + lane * RSTRIDE];
            #pragma unroll
            for (int i = 0; i < 4; ++i) {
                const float4 v = *(const float4*)&rb[i * 4];
                acc[i*4]   += v.x;  acc[i*4+1] += v.y;
                acc[i*4+2] += v.z;  acc[i*4+3] += v.w;
            }
        }

        // ---- overlap-add: t = k*8+j = frames[k][j] + frames[k-1][8+j] ----
        float* ob = out + (size_t)(m * C_ + c) * T_ + (size_t)kk * HOP;
        float cmb[8];
        #pragma unroll
        for (int j = 0; j < 8; ++j) {
            const float pv = __shfl_up(acc[8 + j], 1);   // frames[kk-1][8+j]
            cmb[j] = acc[j] + pv;
        }
        if (lane == 0) {
            float* hb = ws + (size_t)((m * C_ + c) * NB + bb) * 8;
            *(float4*)&hb[0] = make_float4(acc[0], acc[1], acc[2], acc[3]);
            *(float4*)&hb[4] = make_float4(acc[4], acc[5], acc[6], acc[7]);
        } else {
            *(float4*)&ob[0] = make_float4(cmb[0], cmb[1], cmb[2], cmb[3]);
            *(float4*)&ob[4] = make_float4(cmb[4], cmb[5], cmb[6], cmb[7]);
        }
        if (lane == 63) {
            float* tb = ws + WS_TAIL_OFF + (size_t)((m * C_ + c) * NB + bb) * 8;
            *(float4*)&tb[0] = make_float4(acc[8],  acc[9],  acc[10], acc[11]);
            *(float4*)&tb[4] = make_float4(acc[12], acc[13], acc[14], acc[15]);
        }
    }
}

// out[bb*512 + j] = head[bb] + tail[bb-1]; global tail = tail[NB-1].
__global__ __launch_bounds__(256)
void boundary_kernel(const float* __restrict__ ws, float* __restrict__ out) {
    const int id = blockIdx.x * 256 + threadIdx.x;
    const int total = M_ * C_ * NB * 8;
    if (id >= total) return;
    const int j  = id & 7;
    const int bb = (id >> 3) % NB;
    const int mc = (id >> 3) / NB;
    float v = ws[(size_t)(mc * NB + bb) * 8 + j];
    if (bb > 0) v += ws[WS_TAIL_OFF + (size_t)(mc * NB + bb - 1) * 8 + j];
    out[(size_t)mc * T_ + (size_t)bb * (BK * HOP) + j] = v;
    if (bb == NB - 1) {
        out[(size_t)mc * T_ + (size_t)K_ * HOP + j] =
            ws[WS_TAIL_OFF + (size_t)(mc * NB + bb) * 8 + j];
    }
}

extern "C" void kernel_launch(void* const* d_in, const int* in_sizes, int n_in,
                              void* d_out, int out_size, void* d_ws, size_t ws_size,
                              hipStream_t stream) {
    const float* mix  = (const float*)d_in[0];
    const float* mask = (const float*)d_in[1];
    const float* Wg   = (const float*)d_in[2];
    float* out = (float*)d_out;
    float* ws  = (float*)d_ws;

    decoder_kernel<<<dim3(GRID), dim3(256), 0, stream>>>(mix, mask, Wg, out, ws);
    boundary_kernel<<<dim3((M_ * C_ * NB * 8 + 255) / 256), dim3(256), 0, stream>>>(ws, out);
}